// Round 2
// 813.394 us; speedup vs baseline: 1.0314x; 1.0314x over previous
//
#include <hip/hip_runtime.h>

// Haar wavelet: x (16,32,512,512) f32 -> out (16,128,256,256) f32.
// Each thread processes a 2(h)x4(w) input patch = 2 output columns,
// via two 16B loads and four 8B stores. Fully coalesced.
//
// Nontemporal (nt) cache hints on all loads and stores: the kernel streams
// 1.07 GB exactly once with zero reuse, so bypassing L2/L3 allocation avoids
// write-allocate + dirty-evict overhead on the output stream and keeps the
// input stream from churning the caches.
//
// NOTE: __builtin_nontemporal_* requires native clang vector types, not
// HIP_vector_type classes — hence the ext_vector_type aliases below.

#define B  16
#define C  32
#define H  512
#define W  512
#define H2 256
#define W2 256

typedef float f32x4 __attribute__((ext_vector_type(4)));
typedef float f32x2 __attribute__((ext_vector_type(2)));

__global__ __launch_bounds__(256) void haar_kernel(const float* __restrict__ x,
                                                   float* __restrict__ out) {
    const unsigned t = blockIdx.x * blockDim.x + threadIdx.x;

    // Each thread: 2 output columns. Per (b,c,h2) row there are W2/2 = 128 threads.
    const unsigned wp = t & 127;          // pair-of-output-columns index (0..127)
    const unsigned h2 = (t >> 7) & 255;   // output row (0..255)
    const unsigned bc = t >> 15;          // fused batch*channel (0..511)
    const unsigned b  = bc >> 5;
    const unsigned ch = bc & 31;

    // Input: rows 2*h2 and 2*h2+1, columns 4*wp .. 4*wp+3
    const size_t in_base = ((size_t)bc * H + 2u * h2) * W + 4u * wp;
    const f32x4 r0 = __builtin_nontemporal_load((const f32x4*)(x + in_base));     // a0 b0 a1 b1
    const f32x4 r1 = __builtin_nontemporal_load((const f32x4*)(x + in_base + W)); // c0 d0 c1 d1

    const float a0 = r0.x, b0 = r0.y, a1 = r0.z, b1 = r0.w;
    const float c0 = r1.x, d0 = r1.y, c1 = r1.z, d1 = r1.w;

    f32x2 pooled, dh, dv, dd;
    pooled.x = (a0 + b0 + c0 + d0) * 0.25f;
    pooled.y = (a1 + b1 + c1 + d1) * 0.25f;
    dh.x     = (a0 + b0 - c0 - d0) * 0.5f;
    dh.y     = (a1 + b1 - c1 - d1) * 0.5f;
    dv.x     = (a0 + c0 - b0 - d0) * 0.5f;
    dv.y     = (a1 + c1 - b1 - d1) * 0.5f;
    dd.x     = a0 - b0 - c0 + d0;
    dd.y     = a1 - b1 - c1 + d1;

    // Output: group g lives at channel g*32 + ch
    const size_t grp_stride = (size_t)C * H2 * W2;                 // 32*256*256
    const size_t out_base =
        (((size_t)b * (4 * C) + ch) * H2 + h2) * W2 + 2u * wp;

    __builtin_nontemporal_store(pooled, (f32x2*)(out + out_base + 0 * grp_stride));
    __builtin_nontemporal_store(dh,     (f32x2*)(out + out_base + 1 * grp_stride));
    __builtin_nontemporal_store(dv,     (f32x2*)(out + out_base + 2 * grp_stride));
    __builtin_nontemporal_store(dd,     (f32x2*)(out + out_base + 3 * grp_stride));
}

extern "C" void kernel_launch(void* const* d_in, const int* in_sizes, int n_in,
                              void* d_out, int out_size, void* d_ws, size_t ws_size,
                              hipStream_t stream) {
    const float* x = (const float*)d_in[0];
    float* out = (float*)d_out;

    // Total threads: B*C*H2*(W2/2) = 16*32*256*128 = 16,777,216
    const unsigned total = B * C * H2 * (W2 / 2);
    const unsigned block = 256;
    const unsigned grid = total / block;   // 65536

    haar_kernel<<<grid, block, 0, stream>>>(x, out);
}